// Round 1
// baseline (600.997 us; speedup 1.0000x reference)
//
#include <hip/hip_runtime.h>
#include <math.h>

// Problem constants (fixed by the reference)
constexpr int NG    = 128;          // graphs
constexpr int NP    = 1024;         // nodes per graph
constexpr int D     = 256;          // feature dim
constexpr int NTOT  = NG * NP;      // 131072 nodes
constexpr int ET    = NTOT * 32;    // 4194304 edges
constexpr int KK    = 820;          // kept per graph
constexpr int NKEEP = NG * KK;      // 104960 kept nodes

// Output layout (flat float32, reference return order)
constexpr long long OUT_X     = 0;
constexpr long long OUT_EI0   = (long long)NKEEP * D;     // 26869760
constexpr long long OUT_EI1   = OUT_EI0 + ET;
constexpr long long OUT_MASK  = OUT_EI0 + 2LL * ET;
constexpr long long OUT_BATCH = OUT_MASK + ET;
constexpr long long OUT_PERM  = OUT_BATCH + NKEEP;        // total 39662592

// ---------------------------------------------------------------------------
// 1) h[i] = dot(x[i,:], W)  (one 64-lane wave per row, float4 loads)
//    + init deg=1.0 (self-loop), new_id=-1
__global__ void node_init_kernel(const float* __restrict__ x,
                                 const float* __restrict__ W,
                                 float* __restrict__ h,
                                 float* __restrict__ deg,
                                 int* __restrict__ new_id) {
    int row  = blockIdx.x * 4 + (threadIdx.x >> 6);   // 4 rows / 256-thr block
    int lane = threadIdx.x & 63;
    float4 a = ((const float4*)(x + (size_t)row * D))[lane];
    float4 w = ((const float4*)W)[lane];
    float s = a.x * w.x + a.y * w.y + a.z * w.z + a.w * w.w;
#pragma unroll
    for (int off = 32; off > 0; off >>= 1) s += __shfl_down(s, off, 64);
    if (lane == 0) {
        h[row]      = s;
        deg[row]    = 1.0f;   // self-loop contribution to degree
        new_id[row] = -1;
    }
}

// 2) deg[col] += 1 per edge (target region is 512KB -> L2-resident atomics)
__global__ void deg_kernel(const int* __restrict__ col, float* __restrict__ deg) {
    int t = blockIdx.x * blockDim.x + threadIdx.x;    // handles 4 edges
    int4 c = ((const int4*)col)[t];
    atomicAdd(&deg[c.x], 1.0f);
    atomicAdd(&deg[c.y], 1.0f);
    atomicAdd(&deg[c.z], 1.0f);
    atomicAdd(&deg[c.w], 1.0f);
}

// 3) dinv = 1/sqrt(deg); score = dinv^2*h + b  (self-loop + bias init)
__global__ void dinv_kernel(const float* __restrict__ deg,
                            const float* __restrict__ h,
                            const float* __restrict__ b,
                            float* __restrict__ dinv,
                            float* __restrict__ score) {
    int i = blockIdx.x * blockDim.x + threadIdx.x;
    float d  = deg[i];
    float di = 1.0f / sqrtf(d);
    dinv[i]  = di;
    score[i] = di * di * h[i] + b[0];
}

// 4) score[col] += dinv[row]*dinv[col]*h[row] per edge
__global__ void agg_kernel(const int* __restrict__ row, const int* __restrict__ col,
                           const float* __restrict__ dinv, const float* __restrict__ h,
                           float* __restrict__ score) {
    int t = blockIdx.x * blockDim.x + threadIdx.x;    // 4 edges
    int4 r = ((const int4*)row)[t];
    int4 c = ((const int4*)col)[t];
    atomicAdd(&score[c.x], dinv[r.x] * dinv[c.x] * h[r.x]);
    atomicAdd(&score[c.y], dinv[r.y] * dinv[c.y] * h[r.y]);
    atomicAdd(&score[c.z], dinv[r.z] * dinv[c.z] * h[r.z]);
    atomicAdd(&score[c.w], dinv[r.w] * dinv[c.w] * h[r.w]);
}

// 5) Per-graph full bitonic sort of 1024 scores in LDS.
//    Order: descending score, ascending index on ties (== lax.top_k semantics).
//    Emits perm (node ids), batch_new (=g), and new_id scatter.
__global__ __launch_bounds__(512) void topk_kernel(const float* __restrict__ score,
                                                   int* __restrict__ perm_i,
                                                   int* __restrict__ new_id,
                                                   float* __restrict__ out_perm,
                                                   float* __restrict__ out_batch) {
    __shared__ float ss[NP];
    __shared__ int   si[NP];
    int g = blockIdx.x;
    int base = g * NP;
    for (int i = threadIdx.x; i < NP; i += 512) { ss[i] = score[base + i]; si[i] = i; }
    __syncthreads();
    for (int k = 2; k <= NP; k <<= 1) {
        for (int j = k >> 1; j > 0; j >>= 1) {
            for (int i = threadIdx.x; i < NP; i += 512) {
                int l = i ^ j;
                if (l > i) {
                    float sv_i = ss[i], sv_l = ss[l];
                    int   id_i = si[i], id_l = si[l];
                    // "l's element should precede i's" in the desired order
                    bool l_first = (sv_l > sv_i) || (sv_l == sv_i && id_l < id_i);
                    if (l_first == ((i & k) == 0)) {
                        ss[i] = sv_l; ss[l] = sv_i;
                        si[i] = id_l; si[l] = id_i;
                    }
                }
            }
            __syncthreads();
        }
    }
    for (int r = threadIdx.x; r < KK; r += 512) {
        int node = base + si[r];
        int j    = g * KK + r;
        perm_i[j]    = node;
        new_id[node] = j;
        out_perm[j]  = (float)node;
        out_batch[j] = (float)g;   // graphs are contiguous: batch[node] == g
    }
}

// 6) x_new[j,:] = x[perm[j],:] * tanh(score[perm[j]])  (float4, 1KB rows)
__global__ void gather_kernel(const float* __restrict__ x,
                              const int* __restrict__ perm_i,
                              const float* __restrict__ score,
                              float* __restrict__ out_x) {
    int j    = blockIdx.x * 4 + (threadIdx.x >> 6);
    int lane = threadIdx.x & 63;
    int node = perm_i[j];
    float t  = tanhf(score[node]);
    float4 v = ((const float4*)(x + (size_t)node * D))[lane];
    float4 o = make_float4(v.x * t, v.y * t, v.z * t, v.w * t);
    ((float4*)(out_x + (size_t)j * D))[lane] = o;
}

// 7) Edge remap: r2=new_id[row], c2=new_id[col]; mask; -1 fill. Floats out.
__global__ void edge_kernel(const int* __restrict__ row, const int* __restrict__ col,
                            const int* __restrict__ new_id,
                            float* __restrict__ out_r, float* __restrict__ out_c,
                            float* __restrict__ out_m) {
    int t = blockIdx.x * blockDim.x + threadIdx.x;    // 4 edges
    int4 r = ((const int4*)row)[t];
    int4 c = ((const int4*)col)[t];
    float4 fr, fc, fm;
    {
        int nr = new_id[r.x], nc = new_id[c.x];
        bool m = (nr >= 0) && (nc >= 0);
        fr.x = m ? (float)nr : -1.0f; fc.x = m ? (float)nc : -1.0f; fm.x = m ? 1.0f : 0.0f;
    }
    {
        int nr = new_id[r.y], nc = new_id[c.y];
        bool m = (nr >= 0) && (nc >= 0);
        fr.y = m ? (float)nr : -1.0f; fc.y = m ? (float)nc : -1.0f; fm.y = m ? 1.0f : 0.0f;
    }
    {
        int nr = new_id[r.z], nc = new_id[c.z];
        bool m = (nr >= 0) && (nc >= 0);
        fr.z = m ? (float)nr : -1.0f; fc.z = m ? (float)nc : -1.0f; fm.z = m ? 1.0f : 0.0f;
    }
    {
        int nr = new_id[r.w], nc = new_id[c.w];
        bool m = (nr >= 0) && (nc >= 0);
        fr.w = m ? (float)nr : -1.0f; fc.w = m ? (float)nc : -1.0f; fm.w = m ? 1.0f : 0.0f;
    }
    ((float4*)out_r)[t] = fr;
    ((float4*)out_c)[t] = fc;
    ((float4*)out_m)[t] = fm;
}

extern "C" void kernel_launch(void* const* d_in, const int* in_sizes, int n_in,
                              void* d_out, int out_size, void* d_ws, size_t ws_size,
                              hipStream_t stream) {
    const float* x  = (const float*)d_in[0];
    const int*   ei = (const int*)d_in[1];
    // d_in[2] (batch) unused: graphs are contiguous so batch[node] = node/NP
    const float* W  = (const float*)d_in[3];
    const float* b  = (const float*)d_in[4];
    float* out = (float*)d_out;

    // Workspace layout (~3 MB; ws is poisoned each call -> everything re-inited)
    float* wsf    = (float*)d_ws;
    float* h      = wsf;
    float* deg    = wsf + NTOT;
    float* dinv   = wsf + 2 * NTOT;
    float* score  = wsf + 3 * NTOT;
    int*   new_id = (int*)wsf + 4 * NTOT;
    int*   perm_i = (int*)wsf + 5 * NTOT;

    const int* rows = ei;        // edge_index[0] = sources
    const int* cols = ei + ET;   // edge_index[1] = targets

    hipLaunchKernelGGL(node_init_kernel, dim3(NTOT / 4), dim3(256), 0, stream,
                       x, W, h, deg, new_id);
    hipLaunchKernelGGL(deg_kernel, dim3(ET / 4 / 256), dim3(256), 0, stream,
                       cols, deg);
    hipLaunchKernelGGL(dinv_kernel, dim3(NTOT / 256), dim3(256), 0, stream,
                       deg, h, b, dinv, score);
    hipLaunchKernelGGL(agg_kernel, dim3(ET / 4 / 256), dim3(256), 0, stream,
                       rows, cols, dinv, h, score);
    hipLaunchKernelGGL(topk_kernel, dim3(NG), dim3(512), 0, stream,
                       score, perm_i, new_id, out + OUT_PERM, out + OUT_BATCH);
    hipLaunchKernelGGL(gather_kernel, dim3(NKEEP / 4), dim3(256), 0, stream,
                       x, perm_i, score, out + OUT_X);
    hipLaunchKernelGGL(edge_kernel, dim3(ET / 4 / 256), dim3(256), 0, stream,
                       rows, cols, new_id, out + OUT_EI0, out + OUT_EI1, out + OUT_MASK);
}

// Round 2
// 364.047 us; speedup vs baseline: 1.6509x; 1.6509x over previous
//
#include <hip/hip_runtime.h>
#include <math.h>

// Problem constants (fixed by the reference)
constexpr int NG    = 128;          // graphs
constexpr int NP    = 1024;         // nodes per graph
constexpr int D     = 256;          // feature dim
constexpr int NTOT  = NG * NP;      // 131072 nodes
constexpr int EPG   = NP * 32;      // 32768 edges per graph (contiguous!)
constexpr int ET    = NTOT * 32;    // 4194304 edges
constexpr int KK    = 820;          // kept per graph
constexpr int NKEEP = NG * KK;      // 104960 kept nodes

// Output layout (flat float32, reference return order)
constexpr long long OUT_X     = 0;
constexpr long long OUT_EI0   = (long long)NKEEP * D;     // 26869760
constexpr long long OUT_EI1   = OUT_EI0 + ET;
constexpr long long OUT_MASK  = OUT_EI0 + 2LL * ET;
constexpr long long OUT_BATCH = OUT_MASK + ET;
constexpr long long OUT_PERM  = OUT_BATCH + NKEEP;        // total 39662592

// ---------------------------------------------------------------------------
// 1) h[i] = dot(x[i,:], W)  (one 64-lane wave per row, float4 loads)
//    + init new_id=-1
__global__ void node_init_kernel(const float* __restrict__ x,
                                 const float* __restrict__ W,
                                 float* __restrict__ h,
                                 int* __restrict__ new_id) {
    int row  = blockIdx.x * 4 + (threadIdx.x >> 6);   // 4 rows / 256-thr block
    int lane = threadIdx.x & 63;
    float4 a = ((const float4*)(x + (size_t)row * D))[lane];
    float4 w = ((const float4*)W)[lane];
    float s = a.x * w.x + a.y * w.y + a.z * w.z + a.w * w.w;
#pragma unroll
    for (int off = 32; off > 0; off >>= 1) s += __shfl_down(s, off, 64);
    if (lane == 0) {
        h[row]      = s;
        new_id[row] = -1;
    }
}

// ---------------------------------------------------------------------------
// 2) Fused per-graph pipeline: degree -> dinv -> score scatter -> bitonic topk.
//    One 1024-thread block per graph; ALL atomics are LDS-side (ds_add), no
//    device-coherence round trips. Edges of graph g are the contiguous slice
//    [g*EPG, (g+1)*EPG) and endpoints satisfy local_id = global_id & (NP-1).
__global__ __launch_bounds__(1024) void graph_kernel(
        const int* __restrict__ rows, const int* __restrict__ cols,
        const float* __restrict__ h, const float* __restrict__ b,
        int* __restrict__ perm_i, int* __restrict__ new_id,
        float* __restrict__ factor,
        float* __restrict__ out_perm, float* __restrict__ out_batch) {
    __shared__ float h_l[NP];   // node scores h
    __shared__ float dv[NP];    // dinv
    __shared__ float sc[NP];    // aggregated score (sort key)
    __shared__ int   si[NP];    // degree counter, then sort payload (node idx)

    const int g = blockIdx.x;
    const int t = threadIdx.x;
    const int nbase = g * NP;

    h_l[t] = h[nbase + t];
    si[t]  = 1;                  // self-loop contribution to degree
    __syncthreads();

    // pass 1: degree at target (int LDS atomics)
    const int4* c4 = (const int4*)(cols + (size_t)g * EPG);
    const int4* r4 = (const int4*)(rows + (size_t)g * EPG);
#pragma unroll
    for (int i = t; i < EPG / 4; i += 1024) {
        int4 c = c4[i];
        atomicAdd(&si[c.x & (NP - 1)], 1);
        atomicAdd(&si[c.y & (NP - 1)], 1);
        atomicAdd(&si[c.z & (NP - 1)], 1);
        atomicAdd(&si[c.w & (NP - 1)], 1);
    }
    __syncthreads();

    // dinv, self-loop + bias score init, repurpose si as sort payload
    {
        float di = 1.0f / sqrtf((float)si[t]);
        dv[t] = di;
        sc[t] = di * di * h_l[t] + b[0];
    }
    __syncthreads();
    si[t] = t;
    __syncthreads();

    // pass 2: score[c] += dinv[r]*dinv[c]*h[r]  (float LDS atomics)
#pragma unroll
    for (int i = t; i < EPG / 4; i += 1024) {
        int4 c = c4[i];
        int4 r = r4[i];
        int lc, lr;
        lc = c.x & (NP - 1); lr = r.x & (NP - 1);
        atomicAdd(&sc[lc], dv[lr] * dv[lc] * h_l[lr]);
        lc = c.y & (NP - 1); lr = r.y & (NP - 1);
        atomicAdd(&sc[lc], dv[lr] * dv[lc] * h_l[lr]);
        lc = c.z & (NP - 1); lr = r.z & (NP - 1);
        atomicAdd(&sc[lc], dv[lr] * dv[lc] * h_l[lr]);
        lc = c.w & (NP - 1); lr = r.w & (NP - 1);
        atomicAdd(&sc[lc], dv[lr] * dv[lc] * h_l[lr]);
    }
    __syncthreads();

    // Bitonic sort of (sc, si): descending score, ascending index on ties
    // (matches lax.top_k). 1024 threads, pair (t, t^j) handled by smaller idx.
    for (int k = 2; k <= NP; k <<= 1) {
        for (int j = k >> 1; j > 0; j >>= 1) {
            int l = t ^ j;
            if (l > t) {
                float sv_t = sc[t], sv_l = sc[l];
                int   id_t = si[t], id_l = si[l];
                bool l_first = (sv_l > sv_t) || (sv_l == sv_t && id_l < id_t);
                if (l_first == ((t & k) == 0)) {
                    sc[t] = sv_l; sc[l] = sv_t;
                    si[t] = id_l; si[l] = id_t;
                }
            }
            __syncthreads();
        }
    }

    if (t < KK) {
        int node = nbase + si[t];
        int j    = g * KK + t;
        perm_i[j]    = node;
        new_id[node] = j;
        out_perm[j]  = (float)node;
        out_batch[j] = (float)g;       // graphs contiguous: batch[node] == g
        factor[j]    = tanhf(sc[t]);   // gather scale, precomputed
    }
}

// ---------------------------------------------------------------------------
// 3) x_new[j,:] = x[perm[j],:] * factor[j]  (float4, 1KB rows, coalesced)
__global__ void gather_kernel(const float* __restrict__ x,
                              const int* __restrict__ perm_i,
                              const float* __restrict__ factor,
                              float* __restrict__ out_x) {
    int j    = blockIdx.x * 4 + (threadIdx.x >> 6);
    int lane = threadIdx.x & 63;
    int node = perm_i[j];
    float t  = factor[j];
    float4 v = ((const float4*)(x + (size_t)node * D))[lane];
    float4 o = make_float4(v.x * t, v.y * t, v.z * t, v.w * t);
    ((float4*)(out_x + (size_t)j * D))[lane] = o;
}

// ---------------------------------------------------------------------------
// 4) Edge remap: r2=new_id[row], c2=new_id[col]; mask; -1 fill. Floats out.
__global__ void edge_kernel(const int* __restrict__ row, const int* __restrict__ col,
                            const int* __restrict__ new_id,
                            float* __restrict__ out_r, float* __restrict__ out_c,
                            float* __restrict__ out_m) {
    int t = blockIdx.x * blockDim.x + threadIdx.x;    // 4 edges
    int4 r = ((const int4*)row)[t];
    int4 c = ((const int4*)col)[t];
    float4 fr, fc, fm;
    {
        int nr = new_id[r.x], nc = new_id[c.x];
        bool m = (nr >= 0) && (nc >= 0);
        fr.x = m ? (float)nr : -1.0f; fc.x = m ? (float)nc : -1.0f; fm.x = m ? 1.0f : 0.0f;
    }
    {
        int nr = new_id[r.y], nc = new_id[c.y];
        bool m = (nr >= 0) && (nc >= 0);
        fr.y = m ? (float)nr : -1.0f; fc.y = m ? (float)nc : -1.0f; fm.y = m ? 1.0f : 0.0f;
    }
    {
        int nr = new_id[r.z], nc = new_id[c.z];
        bool m = (nr >= 0) && (nc >= 0);
        fr.z = m ? (float)nr : -1.0f; fc.z = m ? (float)nc : -1.0f; fm.z = m ? 1.0f : 0.0f;
    }
    {
        int nr = new_id[r.w], nc = new_id[c.w];
        bool m = (nr >= 0) && (nc >= 0);
        fr.w = m ? (float)nr : -1.0f; fc.w = m ? (float)nc : -1.0f; fm.w = m ? 1.0f : 0.0f;
    }
    ((float4*)out_r)[t] = fr;
    ((float4*)out_c)[t] = fc;
    ((float4*)out_m)[t] = fm;
}

extern "C" void kernel_launch(void* const* d_in, const int* in_sizes, int n_in,
                              void* d_out, int out_size, void* d_ws, size_t ws_size,
                              hipStream_t stream) {
    const float* x  = (const float*)d_in[0];
    const int*   ei = (const int*)d_in[1];
    // d_in[2] (batch) unused: graphs are contiguous so batch[node] = node/NP
    const float* W  = (const float*)d_in[3];
    const float* b  = (const float*)d_in[4];
    float* out = (float*)d_out;

    // Workspace layout (~1.5 MB; ws is poisoned each call -> everything re-inited)
    float* wsf    = (float*)d_ws;
    float* h      = wsf;                       // [NTOT]
    int*   new_id = (int*)wsf + NTOT;          // [NTOT]
    int*   perm_i = (int*)wsf + 2 * NTOT;      // [NKEEP]
    float* factor = wsf + 2 * NTOT + NKEEP;    // [NKEEP]

    const int* rows = ei;        // edge_index[0] = sources
    const int* cols = ei + ET;   // edge_index[1] = targets

    hipLaunchKernelGGL(node_init_kernel, dim3(NTOT / 4), dim3(256), 0, stream,
                       x, W, h, new_id);
    hipLaunchKernelGGL(graph_kernel, dim3(NG), dim3(1024), 0, stream,
                       rows, cols, h, b, perm_i, new_id, factor,
                       out + OUT_PERM, out + OUT_BATCH);
    hipLaunchKernelGGL(gather_kernel, dim3(NKEEP / 4), dim3(256), 0, stream,
                       x, perm_i, factor, out + OUT_X);
    hipLaunchKernelGGL(edge_kernel, dim3(ET / 4 / 256), dim3(256), 0, stream,
                       rows, cols, new_id, out + OUT_EI0, out + OUT_EI1, out + OUT_MASK);
}

// Round 3
// 355.925 us; speedup vs baseline: 1.6885x; 1.0228x over previous
//
#include <hip/hip_runtime.h>
#include <math.h>

// Problem constants (fixed by the reference)
constexpr int NG    = 128;          // graphs
constexpr int NP    = 1024;         // nodes per graph
constexpr int D     = 256;          // feature dim
constexpr int NTOT  = NG * NP;      // 131072 nodes
constexpr int EPG   = NP * 32;      // 32768 edges per graph (contiguous slice)
constexpr int ET    = NTOT * 32;    // 4194304 edges
constexpr int KK    = 820;          // kept per graph
constexpr int NKEEP = NG * KK;      // 104960 kept nodes

// Output layout (flat float32, reference return order)
constexpr long long OUT_X     = 0;
constexpr long long OUT_EI0   = (long long)NKEEP * D;     // 26869760
constexpr long long OUT_EI1   = OUT_EI0 + ET;
constexpr long long OUT_MASK  = OUT_EI0 + 2LL * ET;
constexpr long long OUT_BATCH = OUT_MASK + ET;
constexpr long long OUT_PERM  = OUT_BATCH + NKEEP;        // total 39662592

// ---------------------------------------------------------------------------
// 1) h[i] = dot(x[i,:], W)  (one 64-lane wave per row, float4 loads)
//    + init new_id=-1. Full grid -> saturates HBM on the 134 MB x read.
__global__ void node_init_kernel(const float* __restrict__ x,
                                 const float* __restrict__ W,
                                 float* __restrict__ h,
                                 int* __restrict__ new_id) {
    int row  = blockIdx.x * 4 + (threadIdx.x >> 6);   // 4 rows / 256-thr block
    int lane = threadIdx.x & 63;
    float4 a = ((const float4*)(x + (size_t)row * D))[lane];
    float4 w = ((const float4*)W)[lane];
    float s = a.x * w.x + a.y * w.y + a.z * w.z + a.w * w.w;
#pragma unroll
    for (int off = 32; off > 0; off >>= 1) s += __shfl_down(s, off, 64);
    if (lane == 0) {
        h[row]      = s;
        new_id[row] = -1;
    }
}

// ---------------------------------------------------------------------------
// 2) Fused per-graph pipeline: degree -> dinv -> scatter -> top-k sort.
//    One 1024-thread block per graph. All atomics LDS-side.
//    Algebra: score[c] = dinv[c] * sum_r u[r] + dinv[c]^2 h[c] + b,
//             u[r] = dinv[r]*h[r]  -> edge pass is acc[c] += u[r] only.
//    Sort: packed u64 key per thread in registers; 45/55 bitonic steps via
//    __shfl_xor (no barrier), 10 cross-wave steps via LDS.
__global__ __launch_bounds__(1024) void graph_kernel(
        const int* __restrict__ rows, const int* __restrict__ cols,
        const float* __restrict__ h, const float* __restrict__ b,
        int* __restrict__ perm_i, int* __restrict__ new_id,
        float* __restrict__ factor,
        float* __restrict__ out_perm, float* __restrict__ out_batch) {
    __shared__ float hl[NP];                 // h, then final score
    __shared__ float uu[NP];                 // dinv*h
    __shared__ float acc[NP];                // edge accumulation
    __shared__ int   degc[NP];               // degree counters
    __shared__ unsigned long long sk[NP];    // sort exchange buffer (8 KB)

    const int g = blockIdx.x;
    const int t = threadIdx.x;
    const int nbase = g * NP;

    hl[t]   = h[nbase + t];
    degc[t] = 1;                  // self-loop contributes 1 to degree
    __syncthreads();

    const int4* c4 = (const int4*)(cols + (size_t)g * EPG);
    const int4* r4 = (const int4*)(rows + (size_t)g * EPG);

    // pass 1: degree at target (int LDS atomics)
#pragma unroll
    for (int i = t; i < EPG / 4; i += 1024) {
        int4 c = c4[i];
        atomicAdd(&degc[c.x & (NP - 1)], 1);
        atomicAdd(&degc[c.y & (NP - 1)], 1);
        atomicAdd(&degc[c.z & (NP - 1)], 1);
        atomicAdd(&degc[c.w & (NP - 1)], 1);
    }
    __syncthreads();

    float di = rsqrtf((float)degc[t]);
    uu[t]  = di * hl[t];
    acc[t] = 0.0f;
    __syncthreads();

    // pass 2: acc[c] += u[r]  (1 LDS read + 1 LDS float atomic per edge)
#pragma unroll
    for (int i = t; i < EPG / 4; i += 1024) {
        int4 c = c4[i];
        int4 r = r4[i];
        atomicAdd(&acc[c.x & (NP - 1)], uu[r.x & (NP - 1)]);
        atomicAdd(&acc[c.y & (NP - 1)], uu[r.y & (NP - 1)]);
        atomicAdd(&acc[c.z & (NP - 1)], uu[r.z & (NP - 1)]);
        atomicAdd(&acc[c.w & (NP - 1)], uu[r.w & (NP - 1)]);
    }
    __syncthreads();

    // final score; store over hl (needed later for tanh of kept nodes)
    float score = di * acc[t] + di * di * hl[t] + b[0];
    hl[t] = score;

    // pack sortable key: ascending u64 == (descending score, ascending idx)
    unsigned int fu = __float_as_uint(score);
    unsigned int s  = (fu & 0x80000000u) ? ~fu : (fu | 0x80000000u); // asc==asc f
    unsigned long long key = ((unsigned long long)(~s) << 32) | (unsigned int)t;

    // bitonic sort, one element per thread
    for (int k = 2; k <= NP; k <<= 1) {
        for (int j = k >> 1; j > 0; j >>= 1) {
            unsigned long long other;
            if (j < 64) {
                other = __shfl_xor(key, j, 64);
            } else {
                sk[t] = key;
                __syncthreads();
                other = sk[t ^ j];
                __syncthreads();
            }
            bool take_min = (((t & k) == 0) == ((t & j) == 0));
            bool omin = other < key;
            key = (take_min == omin) ? other : key;
        }
    }
    // barriers inside the sort ordered hl[] score writes before reads below

    if (t < KK) {
        int idx  = (int)(key & 0xFFFFFFFFull);
        int node = nbase + idx;
        int j    = g * KK + t;
        perm_i[j]    = node;
        new_id[node] = j;
        out_perm[j]  = (float)node;
        out_batch[j] = (float)g;        // graphs contiguous: batch[node] == g
        factor[j]    = tanhf(hl[idx]);  // gather scale, precomputed
    }
}

// ---------------------------------------------------------------------------
// 3) x_new[j,:] = x[perm[j],:] * factor[j]  (float4, 1KB rows, coalesced)
__global__ void gather_kernel(const float* __restrict__ x,
                              const int* __restrict__ perm_i,
                              const float* __restrict__ factor,
                              float* __restrict__ out_x) {
    int j    = blockIdx.x * 4 + (threadIdx.x >> 6);
    int lane = threadIdx.x & 63;
    int node = perm_i[j];
    float t  = factor[j];
    float4 v = ((const float4*)(x + (size_t)node * D))[lane];
    float4 o = make_float4(v.x * t, v.y * t, v.z * t, v.w * t);
    ((float4*)(out_x + (size_t)j * D))[lane] = o;
}

// ---------------------------------------------------------------------------
// 4) Edge remap: r2=new_id[row], c2=new_id[col]; mask; -1 fill. Floats out.
__global__ void edge_kernel(const int* __restrict__ row, const int* __restrict__ col,
                            const int* __restrict__ new_id,
                            float* __restrict__ out_r, float* __restrict__ out_c,
                            float* __restrict__ out_m) {
    int t = blockIdx.x * blockDim.x + threadIdx.x;    // 4 edges
    int4 r = ((const int4*)row)[t];
    int4 c = ((const int4*)col)[t];
    float4 fr, fc, fm;
    {
        int nr = new_id[r.x], nc = new_id[c.x];
        bool m = (nr >= 0) && (nc >= 0);
        fr.x = m ? (float)nr : -1.0f; fc.x = m ? (float)nc : -1.0f; fm.x = m ? 1.0f : 0.0f;
    }
    {
        int nr = new_id[r.y], nc = new_id[c.y];
        bool m = (nr >= 0) && (nc >= 0);
        fr.y = m ? (float)nr : -1.0f; fc.y = m ? (float)nc : -1.0f; fm.y = m ? 1.0f : 0.0f;
    }
    {
        int nr = new_id[r.z], nc = new_id[c.z];
        bool m = (nr >= 0) && (nc >= 0);
        fr.z = m ? (float)nr : -1.0f; fc.z = m ? (float)nc : -1.0f; fm.z = m ? 1.0f : 0.0f;
    }
    {
        int nr = new_id[r.w], nc = new_id[c.w];
        bool m = (nr >= 0) && (nc >= 0);
        fr.w = m ? (float)nr : -1.0f; fc.w = m ? (float)nc : -1.0f; fm.w = m ? 1.0f : 0.0f;
    }
    ((float4*)out_r)[t] = fr;
    ((float4*)out_c)[t] = fc;
    ((float4*)out_m)[t] = fm;
}

extern "C" void kernel_launch(void* const* d_in, const int* in_sizes, int n_in,
                              void* d_out, int out_size, void* d_ws, size_t ws_size,
                              hipStream_t stream) {
    const float* x  = (const float*)d_in[0];
    const int*   ei = (const int*)d_in[1];
    // d_in[2] (batch) unused: graphs are contiguous so batch[node] = node/NP
    const float* W  = (const float*)d_in[3];
    const float* b  = (const float*)d_in[4];
    float* out = (float*)d_out;

    // Workspace layout (~1.5 MB; ws is poisoned each call -> everything re-inited)
    float* wsf    = (float*)d_ws;
    float* h      = wsf;                       // [NTOT]
    int*   new_id = (int*)wsf + NTOT;          // [NTOT]
    int*   perm_i = (int*)wsf + 2 * NTOT;      // [NKEEP]
    float* factor = wsf + 2 * NTOT + NKEEP;    // [NKEEP]

    const int* rows = ei;        // edge_index[0] = sources
    const int* cols = ei + ET;   // edge_index[1] = targets

    hipLaunchKernelGGL(node_init_kernel, dim3(NTOT / 4), dim3(256), 0, stream,
                       x, W, h, new_id);
    hipLaunchKernelGGL(graph_kernel, dim3(NG), dim3(1024), 0, stream,
                       rows, cols, h, b, perm_i, new_id, factor,
                       out + OUT_PERM, out + OUT_BATCH);
    hipLaunchKernelGGL(gather_kernel, dim3(NKEEP / 4), dim3(256), 0, stream,
                       x, perm_i, factor, out + OUT_X);
    hipLaunchKernelGGL(edge_kernel, dim3(ET / 4 / 256), dim3(256), 0, stream,
                       rows, cols, new_id, out + OUT_EI0, out + OUT_EI1, out + OUT_MASK);
}

// Round 4
// 336.120 us; speedup vs baseline: 1.7880x; 1.0589x over previous
//
#include <hip/hip_runtime.h>
#include <math.h>

// Problem constants (fixed by the reference)
constexpr int NG    = 128;          // graphs
constexpr int NP    = 1024;         // nodes per graph
constexpr int D     = 256;          // feature dim
constexpr int NTOT  = NG * NP;      // 131072 nodes
constexpr int EPG   = NP * 32;      // 32768 edges per graph (contiguous slice)
constexpr int ET    = NTOT * 32;    // 4194304 edges
constexpr int KK    = 820;          // kept per graph
constexpr int NKEEP = NG * KK;      // 104960 kept nodes
constexpr int BPG   = 4;            // blocks per graph for edge passes
constexpr int EPB   = EPG / BPG;    // 8192 edges per block
constexpr int NBE   = NG * BPG;     // 512 edge-pass blocks

// Output layout (flat float32, reference return order)
constexpr long long OUT_X     = 0;
constexpr long long OUT_EI0   = (long long)NKEEP * D;     // 26869760
constexpr long long OUT_EI1   = OUT_EI0 + ET;
constexpr long long OUT_MASK  = OUT_EI0 + 2LL * ET;
constexpr long long OUT_BATCH = OUT_MASK + ET;
constexpr long long OUT_PERM  = OUT_BATCH + NKEEP;        // total 39662592

// ---------------------------------------------------------------------------
// 1) h[i] = dot(x[i,:], W)  (one 64-lane wave per row, float4 loads)
//    + init new_id=-1. Full grid -> saturates HBM on the 134 MB x read.
__global__ void node_init_kernel(const float* __restrict__ x,
                                 const float* __restrict__ W,
                                 float* __restrict__ h,
                                 int* __restrict__ new_id) {
    int row  = blockIdx.x * 4 + (threadIdx.x >> 6);   // 4 rows / 256-thr block
    int lane = threadIdx.x & 63;
    float4 a = ((const float4*)(x + (size_t)row * D))[lane];
    float4 w = ((const float4*)W)[lane];
    float s = a.x * w.x + a.y * w.y + a.z * w.z + a.w * w.w;
#pragma unroll
    for (int off = 32; off > 0; off >>= 1) s += __shfl_down(s, off, 64);
    if (lane == 0) {
        h[row]      = s;
        new_id[row] = -1;
    }
}

// ---------------------------------------------------------------------------
// 2) Degree partials: 4 blocks per graph, privatized LDS counters, no global
//    atomics. Block b -> graph b>>2, edge slice (b&3)*EPB.
__global__ __launch_bounds__(256) void deg_part_kernel(const int* __restrict__ cols,
                                                       int* __restrict__ deg_part) {
    __shared__ int cnt[NP];
    const int b = blockIdx.x;
    const int g = b >> 2;
    for (int i = threadIdx.x; i < NP; i += 256) cnt[i] = 0;
    __syncthreads();
    const int4* c4 = (const int4*)(cols + (size_t)g * EPG + (size_t)(b & 3) * EPB);
#pragma unroll
    for (int i = threadIdx.x; i < EPB / 4; i += 256) {   // 8 iters
        int4 c = c4[i];
        atomicAdd(&cnt[c.x & (NP - 1)], 1);
        atomicAdd(&cnt[c.y & (NP - 1)], 1);
        atomicAdd(&cnt[c.z & (NP - 1)], 1);
        atomicAdd(&cnt[c.w & (NP - 1)], 1);
    }
    __syncthreads();
    int* dst = deg_part + (size_t)b * NP;
    for (int i = threadIdx.x; i < NP; i += 256) dst[i] = cnt[i];
}

// ---------------------------------------------------------------------------
// 3) Aggregation partials: each block rebuilds u = rsqrt(deg)*h for its graph
//    from the 4 degree partials (16 KB L2-resident reads), then accumulates
//    acc[c] += u[r] over its 8192-edge slice in private LDS.
__global__ __launch_bounds__(256) void acc_part_kernel(const int* __restrict__ rows,
                                                       const int* __restrict__ cols,
                                                       const float* __restrict__ h,
                                                       const int* __restrict__ deg_part,
                                                       float* __restrict__ acc_part) {
    __shared__ float ul[NP];
    __shared__ float acc[NP];
    const int b = blockIdx.x;
    const int g = b >> 2;
    const int* dp = deg_part + (size_t)g * BPG * NP;
    for (int i = threadIdx.x; i < NP; i += 256) {
        int d = 1 + dp[i] + dp[NP + i] + dp[2 * NP + i] + dp[3 * NP + i];
        ul[i]  = rsqrtf((float)d) * h[g * NP + i];
        acc[i] = 0.0f;
    }
    __syncthreads();
    size_t eoff = (size_t)g * EPG + (size_t)(b & 3) * EPB;
    const int4* c4 = (const int4*)(cols + eoff);
    const int4* r4 = (const int4*)(rows + eoff);
#pragma unroll
    for (int i = threadIdx.x; i < EPB / 4; i += 256) {   // 8 iters
        int4 c = c4[i];
        int4 r = r4[i];
        atomicAdd(&acc[c.x & (NP - 1)], ul[r.x & (NP - 1)]);
        atomicAdd(&acc[c.y & (NP - 1)], ul[r.y & (NP - 1)]);
        atomicAdd(&acc[c.z & (NP - 1)], ul[r.z & (NP - 1)]);
        atomicAdd(&acc[c.w & (NP - 1)], ul[r.w & (NP - 1)]);
    }
    __syncthreads();
    float* dst = acc_part + (size_t)b * NP;
    for (int i = threadIdx.x; i < NP; i += 256) dst[i] = acc[i];
}

// ---------------------------------------------------------------------------
// 4) Combine partials -> score -> register bitonic top-k -> epilogue.
//    One 1024-thread block per graph. 45/55 bitonic steps via __shfl_xor
//    (no barrier), 10 cross-wave steps via LDS.
__global__ __launch_bounds__(1024) void sort_kernel(
        const float* __restrict__ h, const float* __restrict__ b,
        const int* __restrict__ deg_part, const float* __restrict__ acc_part,
        int* __restrict__ perm_i, int* __restrict__ new_id,
        float* __restrict__ factor,
        float* __restrict__ out_perm, float* __restrict__ out_batch) {
    __shared__ unsigned long long sk[NP];    // sort exchange buffer (8 KB)
    __shared__ float scl[NP];                // final scores for epilogue tanh

    const int g = blockIdx.x;
    const int t = threadIdx.x;
    const int*   dp = deg_part + (size_t)g * BPG * NP;
    const float* ap = acc_part + (size_t)g * BPG * NP;

    int   d  = 1 + dp[t] + dp[NP + t] + dp[2 * NP + t] + dp[3 * NP + t];
    float av = ap[t] + ap[NP + t] + ap[2 * NP + t] + ap[3 * NP + t];
    float hv = h[g * NP + t];
    float di = rsqrtf((float)d);
    float score = di * av + di * di * hv + b[0];
    scl[t] = score;

    // pack sortable key: ascending u64 == (descending score, ascending idx)
    unsigned int fu = __float_as_uint(score);
    unsigned int s  = (fu & 0x80000000u) ? ~fu : (fu | 0x80000000u);
    unsigned long long key = ((unsigned long long)(~s) << 32) | (unsigned int)t;

    for (int k = 2; k <= NP; k <<= 1) {
        for (int j = k >> 1; j > 0; j >>= 1) {
            unsigned long long other;
            if (j < 64) {
                other = __shfl_xor(key, j, 64);
            } else {
                sk[t] = key;
                __syncthreads();
                other = sk[t ^ j];
                __syncthreads();
            }
            bool take_min = (((t & k) == 0) == ((t & j) == 0));
            bool omin = other < key;
            key = (take_min == omin) ? other : key;
        }
    }
    // sort's internal barriers ordered scl[] writes before the reads below

    if (t < KK) {
        int idx  = (int)(key & 0xFFFFFFFFull);
        int node = g * NP + idx;
        int j    = g * KK + t;
        perm_i[j]    = node;
        new_id[node] = j;
        out_perm[j]  = (float)node;
        out_batch[j] = (float)g;         // graphs contiguous: batch[node] == g
        factor[j]    = tanhf(scl[idx]);  // gather scale, precomputed
    }
}

// ---------------------------------------------------------------------------
// 5) x_new[j,:] = x[perm[j],:] * factor[j]  (float4, 1KB rows, coalesced)
__global__ void gather_kernel(const float* __restrict__ x,
                              const int* __restrict__ perm_i,
                              const float* __restrict__ factor,
                              float* __restrict__ out_x) {
    int j    = blockIdx.x * 4 + (threadIdx.x >> 6);
    int lane = threadIdx.x & 63;
    int node = perm_i[j];
    float t  = factor[j];
    float4 v = ((const float4*)(x + (size_t)node * D))[lane];
    float4 o = make_float4(v.x * t, v.y * t, v.z * t, v.w * t);
    ((float4*)(out_x + (size_t)j * D))[lane] = o;
}

// ---------------------------------------------------------------------------
// 6) Edge remap with the graph's 4 KB new_id slice staged in LDS.
//    512 blocks, graph-aligned 8192-edge slices; lookups are LDS reads.
__global__ __launch_bounds__(256) void edge_kernel(const int* __restrict__ rows,
                                                   const int* __restrict__ cols,
                                                   const int* __restrict__ new_id,
                                                   float* __restrict__ out_r,
                                                   float* __restrict__ out_c,
                                                   float* __restrict__ out_m) {
    __shared__ int nid[NP];
    const int b = blockIdx.x;
    const int g = b >> 2;
    for (int i = threadIdx.x; i < NP; i += 256) nid[i] = new_id[g * NP + i];
    __syncthreads();
    size_t eoff = (size_t)g * EPG + (size_t)(b & 3) * EPB;
    const int4* r4 = (const int4*)(rows + eoff);
    const int4* c4 = (const int4*)(cols + eoff);
    float4* orr = (float4*)(out_r + eoff);
    float4* occ = (float4*)(out_c + eoff);
    float4* omm = (float4*)(out_m + eoff);
#pragma unroll
    for (int i = threadIdx.x; i < EPB / 4; i += 256) {   // 8 iters
        int4 r = r4[i];
        int4 c = c4[i];
        float4 fr, fc, fm;
        {
            int nr = nid[r.x & (NP - 1)], nc = nid[c.x & (NP - 1)];
            bool m = (nr >= 0) && (nc >= 0);
            fr.x = m ? (float)nr : -1.0f; fc.x = m ? (float)nc : -1.0f; fm.x = m ? 1.0f : 0.0f;
        }
        {
            int nr = nid[r.y & (NP - 1)], nc = nid[c.y & (NP - 1)];
            bool m = (nr >= 0) && (nc >= 0);
            fr.y = m ? (float)nr : -1.0f; fc.y = m ? (float)nc : -1.0f; fm.y = m ? 1.0f : 0.0f;
        }
        {
            int nr = nid[r.z & (NP - 1)], nc = nid[c.z & (NP - 1)];
            bool m = (nr >= 0) && (nc >= 0);
            fr.z = m ? (float)nr : -1.0f; fc.z = m ? (float)nc : -1.0f; fm.z = m ? 1.0f : 0.0f;
        }
        {
            int nr = nid[r.w & (NP - 1)], nc = nid[c.w & (NP - 1)];
            bool m = (nr >= 0) && (nc >= 0);
            fr.w = m ? (float)nr : -1.0f; fc.w = m ? (float)nc : -1.0f; fm.w = m ? 1.0f : 0.0f;
        }
        orr[i] = fr;
        occ[i] = fc;
        omm[i] = fm;
    }
}

extern "C" void kernel_launch(void* const* d_in, const int* in_sizes, int n_in,
                              void* d_out, int out_size, void* d_ws, size_t ws_size,
                              hipStream_t stream) {
    const float* x  = (const float*)d_in[0];
    const int*   ei = (const int*)d_in[1];
    // d_in[2] (batch) unused: graphs are contiguous so batch[node] = node/NP
    const float* W  = (const float*)d_in[3];
    const float* b  = (const float*)d_in[4];
    float* out = (float*)d_out;

    // Workspace layout (~6.4 MB; ws is poisoned each call -> all re-inited)
    float* wsf      = (float*)d_ws;
    float* h        = wsf;                               // [NTOT]
    int*   new_id   = (int*)wsf + NTOT;                  // [NTOT]
    int*   perm_i   = (int*)wsf + 2 * NTOT;              // [NKEEP]
    float* factor   = wsf + 2 * NTOT + NKEEP;            // [NKEEP]
    int*   deg_part = (int*)wsf + 2 * NTOT + 2 * NKEEP;  // [NBE*NP]
    float* acc_part = wsf + 2 * NTOT + 2 * NKEEP + NBE * NP; // [NBE*NP]

    const int* rows = ei;        // edge_index[0] = sources
    const int* cols = ei + ET;   // edge_index[1] = targets

    hipLaunchKernelGGL(node_init_kernel, dim3(NTOT / 4), dim3(256), 0, stream,
                       x, W, h, new_id);
    hipLaunchKernelGGL(deg_part_kernel, dim3(NBE), dim3(256), 0, stream,
                       cols, deg_part);
    hipLaunchKernelGGL(acc_part_kernel, dim3(NBE), dim3(256), 0, stream,
                       rows, cols, h, deg_part, acc_part);
    hipLaunchKernelGGL(sort_kernel, dim3(NG), dim3(1024), 0, stream,
                       h, b, deg_part, acc_part, perm_i, new_id, factor,
                       out + OUT_PERM, out + OUT_BATCH);
    hipLaunchKernelGGL(gather_kernel, dim3(NKEEP / 4), dim3(256), 0, stream,
                       x, perm_i, factor, out + OUT_X);
    hipLaunchKernelGGL(edge_kernel, dim3(NBE), dim3(256), 0, stream,
                       rows, cols, new_id, out + OUT_EI0, out + OUT_EI1, out + OUT_MASK);
}